// Round 2
// baseline (761.282 us; speedup 1.0000x reference)
//
#include <hip/hip_runtime.h>
#include <hip/hip_bf16.h>

#define DEV __device__ __forceinline__

typedef __attribute__((ext_vector_type(8))) short bf16x8;
typedef __attribute__((ext_vector_type(4))) float f32x4;

static constexpr int Bsz = 64, S = 256, H = 1024, E = 512, ENCD = 1024, V = 32000;

DEV unsigned short f2bf(float f) {
    unsigned u = __builtin_bit_cast(unsigned, f);
    unsigned r = (u + 0x7FFFu + ((u >> 16) & 1u)) >> 16;
    return (unsigned short)r;
}
DEV float bf2f(unsigned short us) {
    return __builtin_bit_cast(float, (unsigned)us << 16);
}
DEV float sigmoidf_(float x) { return 1.0f / (1.0f + __expf(-x)); }

DEV void gload_lds16(const unsigned short* g, unsigned short* l) {
    __builtin_amdgcn_global_load_lds(
        (const __attribute__((address_space(1))) unsigned int*)g,
        (__attribute__((address_space(3))) unsigned int*)l, 16, 0, 0);
}

// ---------------------------------------------------------------------------
// f32 -> bf16 bulk convert (8 elems/thread)
// ---------------------------------------------------------------------------
__global__ void convert_bf16_kernel(const float* __restrict__ src,
                                    unsigned short* __restrict__ dst, int n8) {
    int i = blockIdx.x * blockDim.x + threadIdx.x;
    if (i >= n8) return;
    float4 f0 = ((const float4*)src)[(size_t)i * 2];
    float4 f1 = ((const float4*)src)[(size_t)i * 2 + 1];
    bf16x8 v;
    v[0]=f2bf(f0.x); v[1]=f2bf(f0.y); v[2]=f2bf(f0.z); v[3]=f2bf(f0.w);
    v[4]=f2bf(f1.x); v[5]=f2bf(f1.y); v[6]=f2bf(f1.z); v[7]=f2bf(f1.w);
    ((bf16x8*)dst)[i] = v;
}

// ---------------------------------------------------------------------------
// prep: embedding gather + bf16 casts into concatenated A matrices.
// A0  = [emb(512) | ctx(1024) | hidden0(1024)]  (64 x 2560 bf16)
// A1  = [h0(1024) | hidden1(1024)]              (64 x 2048 bf16)
// FEAT= [h1(1024) | ctx(1024)   | emb(512)]     (64 x 2560 bf16)
// ---------------------------------------------------------------------------
__global__ void prep_kernel(const int* __restrict__ tok, const float* __restrict__ hidden,
                            const float* __restrict__ emb,
                            unsigned short* __restrict__ A0, unsigned short* __restrict__ A1,
                            unsigned short* __restrict__ FEAT) {
    int b = blockIdx.x, t = threadIdx.x;
    int tb = tok[b];
    for (int c = t; c < E; c += 256) {
        unsigned short us = f2bf(emb[(size_t)tb * E + c]);
        A0[b * 2560 + c] = us;
        FEAT[b * 2560 + 2048 + c] = us;
    }
    for (int c = t; c < H; c += 256) {
        A0[b * 2560 + 1536 + c] = f2bf(hidden[b * H + c]);
        A1[b * 2048 + 1024 + c] = f2bf(hidden[Bsz * H + b * H + c]);
    }
}

// ---------------------------------------------------------------------------
// keys GEMM (16384x1024x1024 bf16) m97-structure: global_load_lds(16B) into
// linear LDS with pre-swizzled global source, XOR-swizzled ds_read_b128,
// BK=64, 128x128 tile, 4 waves. Fused energy epilogue:
//   energy[row] += sum_h v[h] * tanh(keys[row][h] + query[b][h])
// ---------------------------------------------------------------------------
__global__ __launch_bounds__(256) void keys_energy_kernel(
        const unsigned short* __restrict__ encb, const unsigned short* __restrict__ Wkb,
        const float* __restrict__ query, const float* __restrict__ vvec,
        float* __restrict__ energy) {
    __shared__ __align__(16) unsigned short At[128 * 64];   // 16KB, linear [128][64]
    __shared__ __align__(16) unsigned short Bt[128 * 64];

    int blk = blockIdx.x;
    int xcd = blk & 7, idx = blk >> 3;
    int bn = idx & 7, bml = idx >> 3;
    int bm = xcd * 16 + bml;
    int rm0 = bm * 128, n0 = bn * 128;

    int t = threadIdx.x;
    int lane = t & 63, w = t >> 6;
    int l15 = lane & 15, lg = lane >> 4;
    int wrow = (w >> 1) * 64, wcol = (w & 1) * 64;

    f32x4 acc[4][4];
#pragma unroll
    for (int m = 0; m < 4; ++m)
#pragma unroll
        for (int n = 0; n < 4; ++n) acc[m][n] = (f32x4)0.0f;

    // staging geometry: chunk c = w*4+i covers rows c*8..c*8+7 (1KB of LDS).
    // lane -> row = c*8 + (lane>>3); source col = ((lane&7) ^ (row&7))*8
    // (inverse of the read-side XOR swizzle; LDS dest stays linear).
    int srow = lane >> 3;
    int scol_xor = lane & 7;

    for (int kk = 0; kk < 16; ++kk) {
        int k0 = kk * 64;
        __syncthreads();   // previous tile fully consumed
#pragma unroll
        for (int i = 0; i < 4; ++i) {
            int c = w * 4 + i;
            int row = c * 8 + srow;
            int sc = ((scol_xor ^ (row & 7)) * 8);
            gload_lds16(encb + (size_t)(rm0 + row) * ENCD + k0 + sc, &At[c * 512]);
            gload_lds16(Wkb  + (size_t)(n0  + row) * ENCD + k0 + sc, &Bt[c * 512]);
        }
        __syncthreads();   // compiler drains vmcnt before barrier

#pragma unroll
        for (int ks = 0; ks < 2; ++ks) {
            bf16x8 af[4], bfv[4];
#pragma unroll
            for (int m = 0; m < 4; ++m) {
                int row = wrow + m * 16 + l15;
                int off = row * 128 + ((ks * 64 + lg * 16) ^ ((row & 7) << 4));
                af[m] = *(const bf16x8*)((const char*)At + off);
            }
#pragma unroll
            for (int n = 0; n < 4; ++n) {
                int row = wcol + n * 16 + l15;
                int off = row * 128 + ((ks * 64 + lg * 16) ^ ((row & 7) << 4));
                bfv[n] = *(const bf16x8*)((const char*)Bt + off);
            }
#pragma unroll
            for (int m = 0; m < 4; ++m)
#pragma unroll
                for (int n = 0; n < 4; ++n)
                    acc[m][n] = __builtin_amdgcn_mfma_f32_16x16x32_bf16(af[m], bfv[n], acc[m][n], 0, 0, 0);
        }
    }

    // epilogue: energy[row] += sum_cols v[c]*tanh(acc + query[b][c])
    int b = rm0 >> 8;
    const float* qrow = query + b * H;
#pragma unroll
    for (int m = 0; m < 4; ++m) {
#pragma unroll
        for (int j = 0; j < 4; ++j) {
            int gr = rm0 + wrow + m * 16 + lg * 4 + j;
            float part = 0.f;
#pragma unroll
            for (int nf = 0; nf < 4; ++nf) {
                int gc = n0 + wcol + nf * 16 + l15;
                float val = acc[m][nf][j] + qrow[gc];
                part += vvec[gc] * tanhf(val);
            }
            part += __shfl_xor(part, 1);
            part += __shfl_xor(part, 2);
            part += __shfl_xor(part, 4);
            part += __shfl_xor(part, 8);
            if (l15 == 0) atomicAdd(&energy[gr], part);
        }
    }
}

// ---------------------------------------------------------------------------
// masked softmax over S=256 + context = attn @ enc (bf16 enc). grid = 64.
// ---------------------------------------------------------------------------
__global__ __launch_bounds__(256) void softmax_ctx_kernel(
        const float* __restrict__ energy, const int* __restrict__ mask,
        const unsigned short* __restrict__ encb, float* __restrict__ attn_out,
        unsigned short* __restrict__ A0, unsigned short* __restrict__ FEAT) {
    int b = blockIdx.x, t = threadIdx.x;
    __shared__ float wsm[256];
    __shared__ float red[8];

    float e = energy[b * S + t];
    if (mask[b * S + t] == 0) e = -1e10f;
    float m = e;
#pragma unroll
    for (int o = 32; o > 0; o >>= 1) m = fmaxf(m, __shfl_xor(m, o));
    if ((t & 63) == 0) red[t >> 6] = m;
    __syncthreads();
    float mx = fmaxf(fmaxf(red[0], red[1]), fmaxf(red[2], red[3]));
    float ex = __expf(e - mx);
    float sm = ex;
#pragma unroll
    for (int o = 32; o > 0; o >>= 1) sm += __shfl_xor(sm, o);
    if ((t & 63) == 0) red[4 + (t >> 6)] = sm;
    __syncthreads();
    float sum = red[4] + red[5] + red[6] + red[7];
    float wt = ex / sum;
    wsm[t] = wt;
    attn_out[b * S + t] = wt;
    __syncthreads();

    int c = t * 4;
    float a0 = 0.f, a1 = 0.f, a2 = 0.f, a3 = 0.f;
    const unsigned short* ep = encb + (size_t)b * S * ENCD + c;
#pragma unroll 4
    for (int s2 = 0; s2 < S; ++s2) {
        float w_ = wsm[s2];
        ushort4 u = *(const ushort4*)(ep + (size_t)s2 * ENCD);
        a0 += w_ * bf2f(u.x); a1 += w_ * bf2f(u.y);
        a2 += w_ * bf2f(u.z); a3 += w_ * bf2f(u.w);
    }
    unsigned short o0 = f2bf(a0), o1 = f2bf(a1), o2 = f2bf(a2), o3 = f2bf(a3);
    A0[b * 2560 + 512 + c] = o0;  A0[b * 2560 + 512 + c + 1] = o1;
    A0[b * 2560 + 512 + c + 2] = o2; A0[b * 2560 + 512 + c + 3] = o3;
    FEAT[b * 2560 + 1024 + c] = o0; FEAT[b * 2560 + 1024 + c + 1] = o1;
    FEAT[b * 2560 + 1024 + c + 2] = o2; FEAT[b * 2560 + 1024 + c + 3] = o3;
}

// ---------------------------------------------------------------------------
// skinny GEMM (K-split, LDS reduce) for query/gates: C[64][N] =
// A_bf16[64][K1+K2] @ [W1|W2]^T (+b1+b2). NT=16 cols/block, 4 waves split K.
// ---------------------------------------------------------------------------
template <int NT>
__global__ __launch_bounds__(256) void gemm_skinny_kernel(
        const unsigned short* __restrict__ A, int lda,
        const float* __restrict__ W1, int K1,
        const float* __restrict__ W2, int K2,
        const float* __restrict__ b1, const float* __restrict__ b2,
        float* __restrict__ C, int ldc) {
    constexpr int NF = NT / 16;
    __shared__ float red[4 * 64 * NT];

    int n0 = blockIdx.x * NT;
    int t = threadIdx.x, w = t >> 6, lane = t & 63;
    int l15 = lane & 15, lg = lane >> 4;
    int K = K1 + K2, Kw = K >> 2;
    int kbeg = w * Kw, kend = kbeg + Kw;

    f32x4 acc[4][NF];
#pragma unroll
    for (int m = 0; m < 4; ++m)
#pragma unroll
        for (int nf = 0; nf < NF; ++nf) acc[m][nf] = (f32x4)0.0f;

    for (int k0 = kbeg; k0 < kend; k0 += 32) {
        bf16x8 af[4];
#pragma unroll
        for (int m = 0; m < 4; ++m)
            af[m] = *(const bf16x8*)&A[(size_t)(m * 16 + l15) * lda + k0 + lg * 8];

#pragma unroll
        for (int nf = 0; nf < NF; ++nf) {
            int n = n0 + nf * 16 + l15;
            const float* base = (k0 < K1) ? (W1 + (size_t)n * K1 + k0 + lg * 8)
                                          : (W2 + (size_t)n * K2 + (k0 - K1) + lg * 8);
            float4 f0 = *(const float4*)base;
            float4 f1 = *(const float4*)(base + 4);
            bf16x8 bv;
            bv[0]=f2bf(f0.x); bv[1]=f2bf(f0.y); bv[2]=f2bf(f0.z); bv[3]=f2bf(f0.w);
            bv[4]=f2bf(f1.x); bv[5]=f2bf(f1.y); bv[6]=f2bf(f1.z); bv[7]=f2bf(f1.w);
#pragma unroll
            for (int m = 0; m < 4; ++m)
                acc[m][nf] = __builtin_amdgcn_mfma_f32_16x16x32_bf16(af[m], bv, acc[m][nf], 0, 0, 0);
        }
    }

    float* myred = red + w * 64 * NT;
#pragma unroll
    for (int m = 0; m < 4; ++m)
#pragma unroll
        for (int nf = 0; nf < NF; ++nf)
#pragma unroll
            for (int j = 0; j < 4; ++j)
                myred[(m * 16 + lg * 4 + j) * NT + nf * 16 + l15] = acc[m][nf][j];
    __syncthreads();

    for (int o = t; o < 64 * NT; o += 256) {
        int row = o / NT, col = o % NT;
        float s = red[o] + red[64 * NT + o] + red[2 * 64 * NT + o] + red[3 * 64 * NT + o];
        int n = n0 + col;
        if (b1) s += b1[n];
        if (b2) s += b2[n];
        C[(size_t)row * ldc + n] = s;
    }
}

// ---------------------------------------------------------------------------
// wide streaming GEMM for the output projection: C[64][N] = A@W^T + bias.
// N-split: 4 waves x 16 cols, no LDS, register-double-buffered W loads.
// ---------------------------------------------------------------------------
__global__ __launch_bounds__(256) void gemm_wide_kernel(
        const unsigned short* __restrict__ A, int lda, int K,
        const float* __restrict__ W, const float* __restrict__ bias,
        float* __restrict__ C, int ldc) {
    int t = threadIdx.x, w = t >> 6, lane = t & 63;
    int l15 = lane & 15, lg = lane >> 4;
    int n = blockIdx.x * 64 + w * 16 + l15;

    const float* wp = W + (size_t)n * K + lg * 8;
    f32x4 acc[4];
#pragma unroll
    for (int m = 0; m < 4; ++m) acc[m] = (f32x4)0.0f;

    float4 c0 = *(const float4*)(wp);
    float4 c1 = *(const float4*)(wp + 4);
    for (int k0 = 0; k0 < K; k0 += 32) {
        float4 n0_ = c0, n1_ = c1;
        if (k0 + 32 < K) {
            n0_ = *(const float4*)(wp + 32);
            n1_ = *(const float4*)(wp + 36);
        }
        bf16x8 bv;
        bv[0]=f2bf(c0.x); bv[1]=f2bf(c0.y); bv[2]=f2bf(c0.z); bv[3]=f2bf(c0.w);
        bv[4]=f2bf(c1.x); bv[5]=f2bf(c1.y); bv[6]=f2bf(c1.z); bv[7]=f2bf(c1.w);
        bf16x8 af[4];
#pragma unroll
        for (int m = 0; m < 4; ++m)
            af[m] = *(const bf16x8*)&A[(size_t)(m * 16 + l15) * lda + k0 + lg * 8];
#pragma unroll
        for (int m = 0; m < 4; ++m)
            acc[m] = __builtin_amdgcn_mfma_f32_16x16x32_bf16(af[m], bv, acc[m], 0, 0, 0);
        c0 = n0_; c1 = n1_; wp += 32;
    }

    float bs = bias ? bias[n] : 0.f;
#pragma unroll
    for (int m = 0; m < 4; ++m)
#pragma unroll
        for (int j = 0; j < 4; ++j)
            C[(size_t)(m * 16 + lg * 4 + j) * ldc + n] = acc[m][j] + bs;
}

// ---------------------------------------------------------------------------
// LSTM activations
// ---------------------------------------------------------------------------
__global__ void lstm_act_kernel(const float* __restrict__ gates, const float* __restrict__ cell_in,
                                float* __restrict__ h_out, float* __restrict__ c_out,
                                unsigned short* __restrict__ hbf, int hbf_stride) {
    int b = blockIdx.x, t = threadIdx.x;
    for (int c = t; c < H; c += 256) {
        float gi = gates[b * 4096 + c];
        float gf = gates[b * 4096 + 1024 + c];
        float gg = gates[b * 4096 + 2048 + c];
        float go = gates[b * 4096 + 3072 + c];
        float cn = sigmoidf_(gf) * cell_in[b * H + c] + sigmoidf_(gi) * tanhf(gg);
        float hn = sigmoidf_(go) * tanhf(cn);
        c_out[b * H + c] = cn;
        h_out[b * H + c] = hn;
        hbf[b * hbf_stride + c] = f2bf(hn);
    }
}

// ---------------------------------------------------------------------------
extern "C" void kernel_launch(void* const* d_in, const int* in_sizes, int n_in,
                              void* d_out, int out_size, void* d_ws, size_t ws_size,
                              hipStream_t stream) {
    const int*   tok   = (const int*)d_in[0];
    const float* hidden= (const float*)d_in[1];
    const float* cell  = (const float*)d_in[2];
    const float* enc   = (const float*)d_in[3];
    const int*   mask  = (const int*)d_in[4];
    const float* emb   = (const float*)d_in[5];
    const float* Wq    = (const float*)d_in[6];
    const float* Wk    = (const float*)d_in[7];
    const float* vvec  = (const float*)d_in[8];
    const float* Wih0  = (const float*)d_in[9];
    const float* Whh0  = (const float*)d_in[10];
    const float* bih0  = (const float*)d_in[11];
    const float* bhh0  = (const float*)d_in[12];
    const float* Wih1  = (const float*)d_in[13];
    const float* Whh1  = (const float*)d_in[14];
    const float* bih1  = (const float*)d_in[15];
    const float* bhh1  = (const float*)d_in[16];
    const float* Wout  = (const float*)d_in[17];
    const float* bout  = (const float*)d_in[18];

    float* out      = (float*)d_out;
    float* pred     = out;
    float* hid_out  = out + (size_t)Bsz * V;
    float* cell_out = hid_out + 2 * Bsz * H;
    float* attn_out = cell_out + 2 * Bsz * H;

    char* ws = (char*)d_ws;
    float* query  = (float*)ws;                                    // 256KB
    float* energy = query + Bsz * H;                               // 64KB
    float* gates  = energy + Bsz * S;                              // 1MB
    unsigned short* A0   = (unsigned short*)(gates + Bsz * 4096);  // 320KB
    unsigned short* A1   = A0 + Bsz * 2560;                        // 256KB
    unsigned short* FEAT = A1 + Bsz * 2048;                        // 320KB
    unsigned short* encb = FEAT + Bsz * 2560;                      // 32MB
    unsigned short* Wkb  = encb + (size_t)Bsz * S * ENCD;          // 2MB

    convert_bf16_kernel<<<(Bsz * S * ENCD / 8) / 256, 256, 0, stream>>>(enc, encb, Bsz * S * ENCD / 8);
    convert_bf16_kernel<<<(H * ENCD / 8) / 256, 256, 0, stream>>>(Wk, Wkb, H * ENCD / 8);
    hipMemsetAsync(energy, 0, (size_t)Bsz * S * sizeof(float), stream);
    prep_kernel<<<Bsz, 256, 0, stream>>>(tok, hidden, emb, A0, A1, FEAT);

    // query = hidden[1] @ Wq^T
    gemm_skinny_kernel<16><<<H / 16, 256, 0, stream>>>(
        A1 + 1024, 2048, Wq, 1024, nullptr, 0, nullptr, nullptr, query, H);

    keys_energy_kernel<<<1024, 256, 0, stream>>>(encb, Wkb, query, vvec, energy);

    softmax_ctx_kernel<<<Bsz, 256, 0, stream>>>(energy, mask, encb, attn_out, A0, FEAT);

    gemm_skinny_kernel<16><<<4096 / 16, 256, 0, stream>>>(
        A0, 2560, Wih0, 1536, Whh0, 1024, bih0, bhh0, gates, 4096);
    lstm_act_kernel<<<Bsz, 256, 0, stream>>>(gates, cell, hid_out, cell_out, A1, 2048);

    gemm_skinny_kernel<16><<<4096 / 16, 256, 0, stream>>>(
        A1, 2048, Wih1, 1024, Whh1, 1024, bih1, bhh1, gates, 4096);
    lstm_act_kernel<<<Bsz, 256, 0, stream>>>(gates, cell + Bsz * H, hid_out + Bsz * H,
                                             cell_out + Bsz * H, FEAT, 2560);

    gemm_wide_kernel<<<V / 64, 256, 0, stream>>>(
        FEAT, 2560, 2560, Wout, bout, pred, V);
}